// Round 1
// baseline (516.781 us; speedup 1.0000x reference)
//
#include <hip/hip_runtime.h>

#define N_NODES 20000
#define C 64
#define E_EDGES 320000
#define S_SPEC 64
#define R_DIM 8
#define HR 64
#define HEADS 2
#define TE 64
#define INV_AVG (1.0f/16.0f)

// out layout: node_out [0,40000) ; f_s [40000, 1320000) ; f_v [1320000, 5160000)
#define FS_OFF 40000
#define FV_OFF 1320000

__device__ __forceinline__ float bf2f(unsigned short b){
  return __uint_as_float(((unsigned)b) << 16);
}
__device__ __forceinline__ unsigned short f2bf(float f){
  unsigned u = __float_as_uint(f);
  u += 0x7fffu + ((u >> 16) & 1u);
  return (unsigned short)(u >> 16);
}
// phi(x) with SOFT=2 folded in: n = x/2; sus(n) = n>0 ? exp(-1/n) : 0; phi = 1/(1+n*sus)
__device__ __forceinline__ float phi_f(float x){
  float n = x * 0.5f;
  float s = (n > 0.0f) ? expf(-1.0f/n) : 0.0f;
  return 1.0f / (1.0f + n * s);
}

// ---------------- K1: s_u = fs @ W_up_s ; v_u = fv @ W_up_v  (v_u stored [n][x][c]) ----
__global__ void node_up_kernel(const float* __restrict__ fs, const float* __restrict__ fv,
                               const float* __restrict__ Wus, const float* __restrict__ Wuv,
                               float* __restrict__ s_u, float* __restrict__ v_u){
  const int n = blockIdx.x;
  const int d = threadIdx.x;
  __shared__ float s_l[C];
  __shared__ float v_l[3][C];
  s_l[d] = fs[n*C + d];
  #pragma unroll
  for (int x = 0; x < 3; ++x) v_l[x][d] = fv[(n*C + d)*3 + x];
  __syncthreads();
  float as = 0.f, a0 = 0.f, a1 = 0.f, a2 = 0.f;
  #pragma unroll 4
  for (int c = 0; c < C; ++c){
    float wsv = Wus[c*C + d];
    float wvv = Wuv[c*C + d];
    as += s_l[c] * wsv;
    a0 += v_l[0][c] * wvv;
    a1 += v_l[1][c] * wvv;
    a2 += v_l[2][c] * wvv;
  }
  s_u[n*C + d] = as;
  v_u[(n*3 + 0)*C + d] = a0;
  v_u[(n*3 + 1)*C + d] = a1;
  v_u[(n*3 + 2)*C + d] = a2;
}

// ---------------- K2: fused radial-MLP GEMM + message + atomic scatter, 64 edges/block --
__global__ __launch_bounds__(512) void edge_kernel(
    const float* __restrict__ ev, const float* __restrict__ re,
    const int* __restrict__ senders, const int* __restrict__ receivers,
    const float* __restrict__ Wr1, const float* __restrict__ Wr2,
    const float* __restrict__ s_u, const float* __restrict__ v_u,
    float* __restrict__ a_s, float* __restrict__ a_v)
{
  __shared__ __align__(16) float Wr1_l[R_DIM*HR];        // 2 KB
  __shared__ __align__(16) float Wr2_l[HR*5*C];          // 80 KB
  __shared__ __align__(16) float h_l[HR][TE+4];          // 17.4 KB (pad kills k-stride conflicts)
  __shared__ __align__(16) unsigned short w5_l[TE*5*C];  // 40 KB (bf16)
  __shared__ float u_l[TE][4];
  __shared__ int snd_l[TE];
  __shared__ int rcv_l[TE];

  const int t = threadIdx.x;
  const int e0 = blockIdx.x * TE;

  // stage Wr1 (512 f32, one per thread)
  Wr1_l[t] = Wr1[t];
  // stage Wr2 (20480 f32 = 5120 float4, 10 per thread)
  {
    const float4* src = (const float4*)Wr2;
    float4* dst = (float4*)Wr2_l;
    #pragma unroll
    for (int j = 0; j < 10; ++j) dst[t + 512*j] = src[t + 512*j];
  }
  // per-edge direction + indices
  if (t < TE){
    int e = e0 + t;
    float x = ev[e*3+0], y = ev[e*3+1], z = ev[e*3+2];
    float nr = sqrtf(x*x + y*y + z*z);
    float inv = 1.0f / fmaxf(nr, 1e-9f);
    u_l[t][0] = x*inv; u_l[t][1] = y*inv; u_l[t][2] = z*inv;
    snd_l[t] = senders[e];
    rcv_l[t] = receivers[e];
  }
  __syncthreads();

  // h = silu(re @ Wr1) : thread (e = t&63, q = t>>6) computes k = q*8 .. q*8+7
  {
    int e = t & 63, q = t >> 6;
    const float4* rp = (const float4*)&re[(size_t)(e0 + e)*R_DIM];
    float4 ra = rp[0], rb = rp[1];
    #pragma unroll
    for (int kk = 0; kk < 8; ++kk){
      int k = q*8 + kk;
      float acc = ra.x*Wr1_l[0*HR+k] + ra.y*Wr1_l[1*HR+k] + ra.z*Wr1_l[2*HR+k] + ra.w*Wr1_l[3*HR+k]
                + rb.x*Wr1_l[4*HR+k] + rb.y*Wr1_l[5*HR+k] + rb.z*Wr1_l[6*HR+k] + rb.w*Wr1_l[7*HR+k];
      h_l[k][e] = acc / (1.0f + expf(-acc));   // silu
    }
  }
  __syncthreads();

  // W5[64e, 320] = h[64e, 64k] @ Wr2[64k, 320] ; register tile 4 edges x 10 cols / thread
  {
    const int tm = t & 15;    // edge rows 4*tm..+4
    const int tn = t >> 4;    // col group 10*tn..+10 (0..31)
    float acc[4][10];
    #pragma unroll
    for (int i=0;i<4;i++)
      #pragma unroll
      for (int j=0;j<10;j++) acc[i][j]=0.f;
    const int cb = tn*10;
    for (int k = 0; k < HR; ++k){
      float4 hv = *(const float4*)&h_l[k][tm*4];
      const float* wrow = &Wr2_l[k*320 + cb];
      #pragma unroll
      for (int j=0;j<10;j++){
        float w = wrow[j];
        acc[0][j] += hv.x*w;
        acc[1][j] += hv.y*w;
        acc[2][j] += hv.z*w;
        acc[3][j] += hv.w*w;
      }
    }
    #pragma unroll
    for (int i=0;i<4;i++){
      unsigned short* orow = &w5_l[(tm*4+i)*320 + cb];
      #pragma unroll
      for (int j=0;j<10;j++) orow[j] = f2bf(acc[i][j]);
    }
  }
  __syncthreads();

  // messages + scatter: thread (c = t&63, g = t>>6) does edges g*8..+8
  {
    const int c = t & 63;
    const int g = t >> 6;
    #pragma unroll 2
    for (int ee = 0; ee < 8; ++ee){
      int el = g*8 + ee;
      float u0 = u_l[el][0], u1 = u_l[el][1], u2 = u_l[el][2];
      int snd = snd_l[el], rcv = rcv_l[el];
      float se  = s_u[snd*C + c];
      float ve0 = v_u[(snd*3+0)*C + c];
      float ve1 = v_u[(snd*3+1)*C + c];
      float ve2 = v_u[(snd*3+2)*C + c];
      const unsigned short* wr = &w5_l[el*320];
      float w0 = bf2f(wr[0*C + c]);
      float w1 = bf2f(wr[1*C + c]);
      float w2 = bf2f(wr[2*C + c]);
      float w3 = bf2f(wr[3*C + c]);
      float w4 = bf2f(wr[4*C + c]);
      float dt  = ve0*u0 + ve1*u1 + ve2*u2;
      float cr0 = ve1*u2 - ve2*u1;
      float cr1 = ve2*u0 - ve0*u2;
      float cr2 = ve0*u1 - ve1*u0;
      float ms  = (w0*se + w3*dt) * INV_AVG;
      float mv0 = (w1*ve0 + w2*u0 + w4*cr0) * INV_AVG;
      float mv1 = (w1*ve1 + w2*u1 + w4*cr1) * INV_AVG;
      float mv2 = (w1*ve2 + w2*u2 + w4*cr2) * INV_AVG;
      unsafeAtomicAdd(&a_s[rcv*C + c], ms);
      unsafeAtomicAdd(&a_v[(rcv*3+0)*C + c], mv0);
      unsafeAtomicAdd(&a_v[(rcv*3+1)*C + c], mv1);
      unsafeAtomicAdd(&a_v[(rcv*3+2)*C + c], mv2);
    }
  }
}

// ---------------- K3: down-matvec, product basis, prod-matvec, soft-norm, residual, readout
__global__ void node_post_kernel(
    const float* __restrict__ a_s, const float* __restrict__ a_v,
    const float* __restrict__ fs_in, const float* __restrict__ fv_in,
    const int* __restrict__ species,
    const float* __restrict__ W_rs, const float* __restrict__ W_rv,
    const float* __restrict__ W_ds, const float* __restrict__ W_dv,
    const float* __restrict__ w1s, const float* __restrict__ w1v,
    const float* __restrict__ w2ss, const float* __restrict__ w2vv, const float* __restrict__ w2sv,
    const float* __restrict__ W_ps, const float* __restrict__ W_pv,
    const float* __restrict__ w_read, float* __restrict__ out)
{
  const int n = blockIdx.x;
  const int d = threadIdx.x;
  const int sp = species[n];
  __shared__ float as_l[C];
  __shared__ float av_l[3][C];
  __shared__ float si_l[C];
  __shared__ float vi_l[3][C];
  as_l[d] = a_s[n*C + d];
  #pragma unroll
  for (int x=0;x<3;x++) av_l[x][d] = a_v[(n*3+x)*C + d];
  si_l[d] = fs_in[n*C + d];
  #pragma unroll
  for (int x=0;x<3;x++) vi_l[x][d] = fv_in[(n*C + d)*3 + x];
  __syncthreads();
  const float* Wrs_p = W_rs + sp*C*C;
  const float* Wrv_p = W_rv + sp*C*C;
  float bs=0, bv0=0, bv1=0, bv2=0, rs=0, rv0=0, rv1=0, rv2=0;
  for (int c=0;c<C;++c){
    float wds = W_ds[c*C+d], wdv = W_dv[c*C+d];
    float wrs = Wrs_p[c*C+d], wrv = Wrv_p[c*C+d];
    bs  += as_l[c]*wds;
    bv0 += av_l[0][c]*wdv; bv1 += av_l[1][c]*wdv; bv2 += av_l[2][c]*wdv;
    rs  += si_l[c]*wrs;
    rv0 += vi_l[0][c]*wrv; rv1 += vi_l[1][c]*wrv; rv2 += vi_l[2][c]*wrv;
  }
  // equivariant product basis (correlation <= 2), per-channel species weights
  float vv = bv0*bv0 + bv1*bv1 + bv2*bv2;
  float ps  = w1s[sp*C+d]*bs + w2ss[sp*C+d]*bs*bs + w2vv[sp*C+d]*vv;
  float c1v = w1v[sp*C+d], c2sv = w2sv[sp*C+d];
  float pv0 = c1v*bv0 + c2sv*bs*bv0;
  float pv1 = c1v*bv1 + c2sv*bs*bv1;
  float pv2 = c1v*bv2 + c2sv*bs*bv2;
  __syncthreads();
  as_l[d] = ps; av_l[0][d]=pv0; av_l[1][d]=pv1; av_l[2][d]=pv2;
  __syncthreads();
  float qs=0, qv0=0, qv1=0, qv2=0;
  for (int c=0;c<C;++c){
    float wps = W_ps[c*C+d], wpv = W_pv[c*C+d];
    qs  += as_l[c]*wps;
    qv0 += av_l[0][c]*wpv; qv1 += av_l[1][c]*wpv; qv2 += av_l[2][c]*wpv;
  }
  // soft normalization + residual
  float fsv = qs * phi_f(fabsf(qs)) + rs;
  float nv = sqrtf(qv0*qv0 + qv1*qv1 + qv2*qv2);
  float ph = phi_f(nv);
  float fv0 = qv0*ph + rv0;
  float fv1 = qv1*ph + rv1;
  float fv2 = qv2*ph + rv2;
  out[FS_OFF + n*C + d] = fsv;
  float* fvo = &out[FV_OFF + (size_t)(n*C + d)*3];
  fvo[0]=fv0; fvo[1]=fv1; fvo[2]=fv2;
  // readout heads: wave-wide reduction over 64 channels
  #pragma unroll
  for (int h=0; h<HEADS; ++h){
    float r = fsv * w_read[h*C + d];
    #pragma unroll
    for (int off=32; off>0; off>>=1) r += __shfl_down(r, off);
    if (d == 0) out[n*HEADS + h] = r;
  }
}

extern "C" void kernel_launch(void* const* d_in, const int* in_sizes, int n_in,
                              void* d_out, int out_size, void* d_ws, size_t ws_size,
                              hipStream_t stream)
{
  const float* ev   = (const float*)d_in[0];
  const float* nfs  = (const float*)d_in[1];
  const float* nfv  = (const float*)d_in[2];
  const float* re   = (const float*)d_in[3];
  const int*   spec = (const int*)d_in[4];
  const int*   snd  = (const int*)d_in[5];
  const int*   rcv  = (const int*)d_in[6];
  const float* W_rs = (const float*)d_in[7];
  const float* W_rv = (const float*)d_in[8];
  const float* Wus  = (const float*)d_in[9];
  const float* Wuv  = (const float*)d_in[10];
  const float* Wr1  = (const float*)d_in[11];
  const float* Wr2  = (const float*)d_in[12];
  const float* Wds  = (const float*)d_in[13];
  const float* Wdv  = (const float*)d_in[14];
  const float* w1s  = (const float*)d_in[15];
  const float* w1v  = (const float*)d_in[16];
  const float* w2ss = (const float*)d_in[17];
  const float* w2vv = (const float*)d_in[18];
  const float* w2sv = (const float*)d_in[19];
  const float* Wps  = (const float*)d_in[20];
  const float* Wpv  = (const float*)d_in[21];
  const float* wrd  = (const float*)d_in[22];

  float* out = (float*)d_out;
  float* ws  = (float*)d_ws;
  // ws layout (f32): s_u [0,1.28M) ; v_u [1.28M,5.12M) ; a_s [5.12M,6.4M) ; a_v [6.4M,10.24M)
  float* s_u = ws;
  float* v_u = ws + 1280000;
  float* a_s = ws + 5120000;
  float* a_v = ws + 6400000;

  hipMemsetAsync(a_s, 0, (size_t)5120000*sizeof(float), stream);  // zero a_s + a_v
  node_up_kernel<<<N_NODES, 64, 0, stream>>>(nfs, nfv, Wus, Wuv, s_u, v_u);
  edge_kernel<<<E_EDGES/TE, 512, 0, stream>>>(ev, re, snd, rcv, Wr1, Wr2, s_u, v_u, a_s, a_v);
  node_post_kernel<<<N_NODES, 64, 0, stream>>>(a_s, a_v, nfs, nfv, spec,
      W_rs, W_rv, Wds, Wdv, w1s, w1v, w2ss, w2vv, w2sv, Wps, Wpv, wrd, out);
}

// Round 2
// 503.463 us; speedup vs baseline: 1.0265x; 1.0265x over previous
//
#include <hip/hip_runtime.h>

#define N_NODES 20000
#define C 64
#define E_EDGES 320000
#define S_SPEC 64
#define R_DIM 8
#define HR 64
#define HEADS 2
#define TE 64
#define NTILES (E_EDGES/TE)
#define INV_AVG (1.0f/16.0f)
#define W5S (5*C+1)   // padded w5 row stride (321): 321 % 32 == 1 -> conflict-free

// out layout: node_out [0,40000) ; f_s [40000, 1320000) ; f_v [1320000, 5160000)
#define FS_OFF 40000
#define FV_OFF 1320000

__device__ __forceinline__ unsigned short f2bf(float f){
  unsigned u = __float_as_uint(f);
  u += 0x7fffu + ((u >> 16) & 1u);
  return (unsigned short)(u >> 16);
}
// phi(x) with SOFT=2 folded in
__device__ __forceinline__ float phi_f(float x){
  float n = x * 0.5f;
  float s = (n > 0.0f) ? expf(-1.0f/n) : 0.0f;
  return 1.0f / (1.0f + n * s);
}

// ---------------- K1: s_u = fs @ W_up_s ; v_u = fv @ W_up_v  (4 nodes / 256-thr block) ---
__global__ __launch_bounds__(256) void node_up_kernel(
    const float* __restrict__ fs, const float* __restrict__ fv,
    const float* __restrict__ Wus, const float* __restrict__ Wuv,
    float* __restrict__ s_u, float* __restrict__ v_u){
  const int ni = threadIdx.x >> 6;
  const int d  = threadIdx.x & 63;
  const int n  = blockIdx.x*4 + ni;
  __shared__ float s_l[4][C];
  __shared__ float v_l[4][3][C];
  s_l[ni][d] = fs[n*C + d];
  #pragma unroll
  for (int x = 0; x < 3; ++x) v_l[ni][x][d] = fv[(n*C + d)*3 + x];
  __syncthreads();
  float as = 0.f, a0 = 0.f, a1 = 0.f, a2 = 0.f;
  #pragma unroll 4
  for (int c = 0; c < C; ++c){
    float wsv = Wus[c*C + d];
    float wvv = Wuv[c*C + d];
    as += s_l[ni][c] * wsv;
    a0 += v_l[ni][0][c] * wvv;
    a1 += v_l[ni][1][c] * wvv;
    a2 += v_l[ni][2][c] * wvv;
  }
  s_u[n*C + d] = as;
  v_u[(n*3 + 0)*C + d] = a0;
  v_u[(n*3 + 1)*C + d] = a1;
  v_u[(n*3 + 2)*C + d] = a2;
}

// ---------------- sort pass A: histogram of receivers --------------------------------
__global__ __launch_bounds__(256) void hist_kernel(const int* __restrict__ rcv, int* __restrict__ count){
  int e = blockIdx.x*256 + threadIdx.x;
  atomicAdd(&count[rcv[e]], 1);
}

// ---------------- sort pass B: exclusive scan over 20000 counts (1 block) -------------
__global__ __launch_bounds__(1024) void scan_kernel(const int* __restrict__ count, int* __restrict__ cursor){
  __shared__ int sums[1024];
  const int t = threadIdx.x;
  const int base = t*20;
  int s = 0;
  #pragma unroll 4
  for (int i = 0; i < 20; ++i){ int idx = base+i; if (idx < N_NODES) s += count[idx]; }
  sums[t] = s;
  __syncthreads();
  for (int off = 1; off < 1024; off <<= 1){
    int v = (t >= off) ? sums[t-off] : 0;
    __syncthreads();
    sums[t] += v;
    __syncthreads();
  }
  int run = (t > 0) ? sums[t-1] : 0;
  for (int i = 0; i < 20; ++i){
    int idx = base+i;
    if (idx < N_NODES){ cursor[idx] = run; run += count[idx]; }
  }
}

// ---------------- sort pass C: scatter edges into receiver-sorted arrays --------------
__global__ __launch_bounds__(256) void scatter_kernel(
    const int* __restrict__ snd, const int* __restrict__ rcv,
    const float* __restrict__ ev, const float* __restrict__ re,
    int* __restrict__ cursor,
    int* __restrict__ snd_s, int* __restrict__ rcv_s,
    float* __restrict__ ev_s, float* __restrict__ re_s){
  int e = blockIdx.x*256 + threadIdx.x;
  int r = rcv[e];
  int pos = atomicAdd(&cursor[r], 1);
  snd_s[pos] = snd[e];
  rcv_s[pos] = r;
  ev_s[pos*3+0] = ev[e*3+0];
  ev_s[pos*3+1] = ev[e*3+1];
  ev_s[pos*3+2] = ev[e*3+2];
  const float4* rp = (const float4*)&re[(size_t)e*R_DIM];
  float4 ra = rp[0], rb = rp[1];
  float4* op = (float4*)&re_s[(size_t)pos*R_DIM];
  op[0] = ra; op[1] = rb;
}

// ---------------- K2: fused radial GEMM + message + run-length scatter ----------------
__global__ __launch_bounds__(512) void edge_kernel(
    const float* __restrict__ ev_s, const float* __restrict__ re_s,
    const int* __restrict__ snd_s, const int* __restrict__ rcv_s,
    const float* __restrict__ Wr1, const float* __restrict__ Wr2,
    const float* __restrict__ s_u, const float* __restrict__ v_u,
    float* __restrict__ a_s, float* __restrict__ a_v)
{
  __shared__ __align__(16) float Wr1_l[R_DIM*HR];          // 2 KB
  __shared__ __align__(16) unsigned short Wr2b[HR*5*C];    // 40 KB bf16
  __shared__ __align__(16) float h_l[HR][TE+4];            // 17.4 KB
  __shared__ __align__(16) float w5_l[TE*W5S];             // 80.25 KB f32, stride 321
  __shared__ float u_l[TE][4];
  __shared__ int snd_l[TE];
  __shared__ int rcv_l[TE];

  const int t = threadIdx.x;
  // chunked XCD swizzle: 5000 tiles = 8 XCDs x 625; XCD x owns contiguous sorted range
  const int b = blockIdx.x;
  const int tile = (b & 7) * (NTILES/8) + (b >> 3);
  const int e0 = tile * TE;

  Wr1_l[t] = Wr1[t];
  // stage Wr2 f32 -> bf16 (20480 elems = 512 thr x 10 float4)
  {
    #pragma unroll
    for (int j = 0; j < 10; ++j){
      float4 v = ((const float4*)Wr2)[t + 512*j];
      ushort4 o;
      o.x = f2bf(v.x); o.y = f2bf(v.y); o.z = f2bf(v.z); o.w = f2bf(v.w);
      ((ushort4*)Wr2b)[t + 512*j] = o;
    }
  }
  if (t < TE){
    int e = e0 + t;
    float x = ev_s[e*3+0], y = ev_s[e*3+1], z = ev_s[e*3+2];
    float nr = sqrtf(x*x + y*y + z*z);
    float inv = 1.0f / fmaxf(nr, 1e-9f);
    u_l[t][0] = x*inv; u_l[t][1] = y*inv; u_l[t][2] = z*inv;
    snd_l[t] = snd_s[e];
    rcv_l[t] = rcv_s[e];
  }
  __syncthreads();

  // h = silu(re @ Wr1) : thread (e = t&63, q = t>>6) computes k = q*8 .. q*8+7
  {
    int e = t & 63, q = t >> 6;
    const float4* rp = (const float4*)&re_s[(size_t)(e0 + e)*R_DIM];
    float4 ra = rp[0], rb = rp[1];
    #pragma unroll
    for (int kk = 0; kk < 8; ++kk){
      int k = q*8 + kk;
      float acc = ra.x*Wr1_l[0*HR+k] + ra.y*Wr1_l[1*HR+k] + ra.z*Wr1_l[2*HR+k] + ra.w*Wr1_l[3*HR+k]
                + rb.x*Wr1_l[4*HR+k] + rb.y*Wr1_l[5*HR+k] + rb.z*Wr1_l[6*HR+k] + rb.w*Wr1_l[7*HR+k];
      h_l[k][e] = acc / (1.0f + expf(-acc));   // silu
    }
  }
  __syncthreads();

  // W5[64e,320] = h[64e,64k] @ Wr2[64k,320]; 4 edges x 10 cols / thread; w5 f32 padded
  {
    const int tm = t & 15;
    const int tn = t >> 4;
    float acc[4][10];
    #pragma unroll
    for (int i=0;i<4;i++)
      #pragma unroll
      for (int j=0;j<10;j++) acc[i][j]=0.f;
    const int cb = tn*10;
    for (int k = 0; k < HR; ++k){
      float4 hv = *(const float4*)&h_l[k][tm*4];
      const unsigned short* wrow = &Wr2b[k*320 + cb];
      float w[10];
      #pragma unroll
      for (int jj=0;jj<5;++jj){
        unsigned u = *(const unsigned*)&wrow[jj*2];   // two bf16
        w[2*jj]   = __uint_as_float(u << 16);
        w[2*jj+1] = __uint_as_float(u & 0xffff0000u);
      }
      #pragma unroll
      for (int j=0;j<10;j++){
        acc[0][j] += hv.x*w[j];
        acc[1][j] += hv.y*w[j];
        acc[2][j] += hv.z*w[j];
        acc[3][j] += hv.w*w[j];
      }
    }
    #pragma unroll
    for (int i=0;i<4;i++){
      float* orow = &w5_l[(tm*4+i)*W5S + cb];
      #pragma unroll
      for (int j=0;j<10;j++) orow[j] = acc[i][j];
    }
  }
  __syncthreads();

  // messages + run-length register accumulation + atomic flush on receiver change
  {
    const int c = t & 63;
    const int g = t >> 6;                 // wave-uniform (64-lane waves)
    int cur_r = rcv_l[g*8];
    float ms=0.f, mv0=0.f, mv1=0.f, mv2=0.f;
    #pragma unroll 2
    for (int ee = 0; ee < 8; ++ee){
      int el = g*8 + ee;
      int r = rcv_l[el];                  // non-decreasing (sorted)
      if (r != cur_r){                    // wave-uniform branch
        unsafeAtomicAdd(&a_s[cur_r*C + c],       ms  * INV_AVG);
        unsafeAtomicAdd(&a_v[(cur_r*3+0)*C + c], mv0 * INV_AVG);
        unsafeAtomicAdd(&a_v[(cur_r*3+1)*C + c], mv1 * INV_AVG);
        unsafeAtomicAdd(&a_v[(cur_r*3+2)*C + c], mv2 * INV_AVG);
        ms=mv0=mv1=mv2=0.f; cur_r = r;
      }
      float u0 = u_l[el][0], u1 = u_l[el][1], u2 = u_l[el][2];
      int snd = snd_l[el];
      float se  = s_u[snd*C + c];
      float ve0 = v_u[(snd*3+0)*C + c];
      float ve1 = v_u[(snd*3+1)*C + c];
      float ve2 = v_u[(snd*3+2)*C + c];
      const float* wr = &w5_l[el*W5S];
      float w0 = wr[0*C + c];
      float w1 = wr[1*C + c];
      float w2 = wr[2*C + c];
      float w3 = wr[3*C + c];
      float w4 = wr[4*C + c];
      float dt  = ve0*u0 + ve1*u1 + ve2*u2;
      float cr0 = ve1*u2 - ve2*u1;
      float cr1 = ve2*u0 - ve0*u2;
      float cr2 = ve0*u1 - ve1*u0;
      ms  += w0*se + w3*dt;
      mv0 += w1*ve0 + w2*u0 + w4*cr0;
      mv1 += w1*ve1 + w2*u1 + w4*cr1;
      mv2 += w1*ve2 + w2*u2 + w4*cr2;
    }
    unsafeAtomicAdd(&a_s[cur_r*C + c],       ms  * INV_AVG);
    unsafeAtomicAdd(&a_v[(cur_r*3+0)*C + c], mv0 * INV_AVG);
    unsafeAtomicAdd(&a_v[(cur_r*3+1)*C + c], mv1 * INV_AVG);
    unsafeAtomicAdd(&a_v[(cur_r*3+2)*C + c], mv2 * INV_AVG);
  }
}

// ---------------- K3: down-matvec, product basis, soft-norm, residual, readout (4/blk)
__global__ __launch_bounds__(256) void node_post_kernel(
    const float* __restrict__ a_s, const float* __restrict__ a_v,
    const float* __restrict__ fs_in, const float* __restrict__ fv_in,
    const int* __restrict__ species,
    const float* __restrict__ W_rs, const float* __restrict__ W_rv,
    const float* __restrict__ W_ds, const float* __restrict__ W_dv,
    const float* __restrict__ w1s, const float* __restrict__ w1v,
    const float* __restrict__ w2ss, const float* __restrict__ w2vv, const float* __restrict__ w2sv,
    const float* __restrict__ W_ps, const float* __restrict__ W_pv,
    const float* __restrict__ w_read, float* __restrict__ out)
{
  const int ni = threadIdx.x >> 6;
  const int d  = threadIdx.x & 63;
  const int n  = blockIdx.x*4 + ni;
  const int sp = species[n];
  __shared__ float as_l[4][C];
  __shared__ float av_l[4][3][C];
  __shared__ float si_l[4][C];
  __shared__ float vi_l[4][3][C];
  as_l[ni][d] = a_s[n*C + d];
  #pragma unroll
  for (int x=0;x<3;x++) av_l[ni][x][d] = a_v[(n*3+x)*C + d];
  si_l[ni][d] = fs_in[n*C + d];
  #pragma unroll
  for (int x=0;x<3;x++) vi_l[ni][x][d] = fv_in[(n*C + d)*3 + x];
  __syncthreads();
  const float* Wrs_p = W_rs + sp*C*C;
  const float* Wrv_p = W_rv + sp*C*C;
  float bs=0, bv0=0, bv1=0, bv2=0, rs=0, rv0=0, rv1=0, rv2=0;
  for (int c=0;c<C;++c){
    float wds = W_ds[c*C+d], wdv = W_dv[c*C+d];
    float wrs = Wrs_p[c*C+d], wrv = Wrv_p[c*C+d];
    bs  += as_l[ni][c]*wds;
    bv0 += av_l[ni][0][c]*wdv; bv1 += av_l[ni][1][c]*wdv; bv2 += av_l[ni][2][c]*wdv;
    rs  += si_l[ni][c]*wrs;
    rv0 += vi_l[ni][0][c]*wrv; rv1 += vi_l[ni][1][c]*wrv; rv2 += vi_l[ni][2][c]*wrv;
  }
  float vv = bv0*bv0 + bv1*bv1 + bv2*bv2;
  float ps  = w1s[sp*C+d]*bs + w2ss[sp*C+d]*bs*bs + w2vv[sp*C+d]*vv;
  float c1v = w1v[sp*C+d], c2sv = w2sv[sp*C+d];
  float pv0 = c1v*bv0 + c2sv*bs*bv0;
  float pv1 = c1v*bv1 + c2sv*bs*bv1;
  float pv2 = c1v*bv2 + c2sv*bs*bv2;
  __syncthreads();
  as_l[ni][d] = ps; av_l[ni][0][d]=pv0; av_l[ni][1][d]=pv1; av_l[ni][2][d]=pv2;
  __syncthreads();
  float qs=0, qv0=0, qv1=0, qv2=0;
  for (int c=0;c<C;++c){
    float wps = W_ps[c*C+d], wpv = W_pv[c*C+d];
    qs  += as_l[ni][c]*wps;
    qv0 += av_l[ni][0][c]*wpv; qv1 += av_l[ni][1][c]*wpv; qv2 += av_l[ni][2][c]*wpv;
  }
  float fsv = qs * phi_f(fabsf(qs)) + rs;
  float nv = sqrtf(qv0*qv0 + qv1*qv1 + qv2*qv2);
  float ph = phi_f(nv);
  float fv0 = qv0*ph + rv0;
  float fv1 = qv1*ph + rv1;
  float fv2 = qv2*ph + rv2;
  out[FS_OFF + n*C + d] = fsv;
  float* fvo = &out[FV_OFF + (size_t)(n*C + d)*3];
  fvo[0]=fv0; fvo[1]=fv1; fvo[2]=fv2;
  #pragma unroll
  for (int h=0; h<HEADS; ++h){
    float r = fsv * w_read[h*C + d];
    #pragma unroll
    for (int off=32; off>0; off>>=1) r += __shfl_down(r, off);
    if (d == 0) out[n*HEADS + h] = r;
  }
}

extern "C" void kernel_launch(void* const* d_in, const int* in_sizes, int n_in,
                              void* d_out, int out_size, void* d_ws, size_t ws_size,
                              hipStream_t stream)
{
  const float* ev   = (const float*)d_in[0];
  const float* nfs  = (const float*)d_in[1];
  const float* nfv  = (const float*)d_in[2];
  const float* re   = (const float*)d_in[3];
  const int*   spec = (const int*)d_in[4];
  const int*   snd  = (const int*)d_in[5];
  const int*   rcv  = (const int*)d_in[6];
  const float* W_rs = (const float*)d_in[7];
  const float* W_rv = (const float*)d_in[8];
  const float* Wus  = (const float*)d_in[9];
  const float* Wuv  = (const float*)d_in[10];
  const float* Wr1  = (const float*)d_in[11];
  const float* Wr2  = (const float*)d_in[12];
  const float* Wds  = (const float*)d_in[13];
  const float* Wdv  = (const float*)d_in[14];
  const float* w1s  = (const float*)d_in[15];
  const float* w1v  = (const float*)d_in[16];
  const float* w2ss = (const float*)d_in[17];
  const float* w2vv = (const float*)d_in[18];
  const float* w2sv = (const float*)d_in[19];
  const float* Wps  = (const float*)d_in[20];
  const float* Wpv  = (const float*)d_in[21];
  const float* wrd  = (const float*)d_in[22];

  float* out = (float*)d_out;
  float* ws  = (float*)d_ws;
  // ws layout (f32 units)
  float* s_u   = ws;                       // 1,280,000
  float* v_u   = ws +  1280000;            // 3,840,000
  float* a_s   = ws +  5120000;            // 1,280,000
  float* a_v   = ws +  6400000;            // 3,840,000
  int*   count = (int*)(ws + 10240000);    // 20,000
  int*   cursr = (int*)(ws + 10260000);    // 20,000
  int*   snd_s = (int*)(ws + 10280000);    // 320,000
  int*   rcv_s = (int*)(ws + 10600000);    // 320,000
  float* ev_s  = ws + 10920000;            // 960,000
  float* re_s  = ws + 11880000;            // 2,560,000  (end 14,440,000 = 57.8 MB)

  hipMemsetAsync(a_s, 0, (size_t)5120000*sizeof(float), stream);   // a_s + a_v
  hipMemsetAsync(count, 0, (size_t)N_NODES*sizeof(int), stream);

  node_up_kernel<<<N_NODES/4, 256, 0, stream>>>(nfs, nfv, Wus, Wuv, s_u, v_u);
  hist_kernel<<<E_EDGES/256, 256, 0, stream>>>(rcv, count);
  scan_kernel<<<1, 1024, 0, stream>>>(count, cursr);
  scatter_kernel<<<E_EDGES/256, 256, 0, stream>>>(snd, rcv, ev, re, cursr,
                                                  snd_s, rcv_s, ev_s, re_s);
  edge_kernel<<<NTILES, 512, 0, stream>>>(ev_s, re_s, snd_s, rcv_s, Wr1, Wr2,
                                          s_u, v_u, a_s, a_v);
  node_post_kernel<<<N_NODES/4, 256, 0, stream>>>(a_s, a_v, nfs, nfv, spec,
      W_rs, W_rv, Wds, Wdv, w1s, w1v, w2ss, w2vv, w2sv, Wps, Wpv, wrd, out);
}

// Round 3
// 420.400 us; speedup vs baseline: 1.2293x; 1.1976x over previous
//
#include <hip/hip_runtime.h>

#define N_NODES 20000
#define C 64
#define E_EDGES 320000
#define S_SPEC 64
#define R_DIM 8
#define HR 64
#define HEADS 2
#define TE 128
#define NT (E_EDGES/TE)          // 2500 blocks
#define HPAD 68                  // padded bf16 row stride (k-dim)
#define INV_AVG (1.0f/16.0f)

// out layout: node_out [0,40000) ; f_s [40000, 1320000) ; f_v [1320000, 5160000)
#define FS_OFF 40000
#define FV_OFF 1320000

typedef short bf16x4 __attribute__((ext_vector_type(4)));
typedef float f32x4  __attribute__((ext_vector_type(4)));

__device__ __forceinline__ unsigned short f2bf(float f){
  unsigned u = __float_as_uint(f);
  u += 0x7fffu + ((u >> 16) & 1u);
  return (unsigned short)(u >> 16);
}
__device__ __forceinline__ float phi_f(float x){
  float n = x * 0.5f;
  float s = (n > 0.0f) ? expf(-1.0f/n) : 0.0f;
  return 1.0f / (1.0f + n * s);
}

// ---------------- prep: Wr2T[n][k] = bf16(Wr2[k][n] / AVG)  (320x64) ------------------
__global__ __launch_bounds__(256) void wr2t_kernel(const float* __restrict__ Wr2,
                                                   unsigned short* __restrict__ wr2t){
  int idx = blockIdx.x*256 + threadIdx.x;      // n*64 + k
  int n = idx >> 6, k = idx & 63;
  wr2t[idx] = f2bf(Wr2[k*320 + n] * INV_AVG);
}

// ---------------- K1: s_u = fs @ W_up_s ; v_u = fv @ W_up_v  (4 nodes / 256-thr block) -
__global__ __launch_bounds__(256) void node_up_kernel(
    const float* __restrict__ fs, const float* __restrict__ fv,
    const float* __restrict__ Wus, const float* __restrict__ Wuv,
    float* __restrict__ s_u, float* __restrict__ v_u){
  const int ni = threadIdx.x >> 6;
  const int d  = threadIdx.x & 63;
  const int n  = blockIdx.x*4 + ni;
  __shared__ float s_l[4][C];
  __shared__ float v_l[4][3][C];
  s_l[ni][d] = fs[n*C + d];
  #pragma unroll
  for (int x = 0; x < 3; ++x) v_l[ni][x][d] = fv[(n*C + d)*3 + x];
  __syncthreads();
  float as = 0.f, a0 = 0.f, a1 = 0.f, a2 = 0.f;
  #pragma unroll 4
  for (int c = 0; c < C; ++c){
    float wsv = Wus[c*C + d];
    float wvv = Wuv[c*C + d];
    as += s_l[ni][c] * wsv;
    a0 += v_l[ni][0][c] * wvv;
    a1 += v_l[ni][1][c] * wvv;
    a2 += v_l[ni][2][c] * wvv;
  }
  s_u[n*C + d] = as;
  v_u[(n*3 + 0)*C + d] = a0;
  v_u[(n*3 + 1)*C + d] = a1;
  v_u[(n*3 + 2)*C + d] = a2;
}

// ---------------- sort pass A: histogram of receivers ---------------------------------
__global__ __launch_bounds__(256) void hist_kernel(const int* __restrict__ rcv, int* __restrict__ count){
  int e = blockIdx.x*256 + threadIdx.x;
  atomicAdd(&count[rcv[e]], 1);
}

// ---------------- sort pass B: exclusive scan over 20000 counts (1 block) -------------
__global__ __launch_bounds__(1024) void scan_kernel(const int* __restrict__ count, int* __restrict__ cursor){
  __shared__ int sums[1024];
  const int t = threadIdx.x;
  const int base = t*20;
  int s = 0;
  #pragma unroll 4
  for (int i = 0; i < 20; ++i){ int idx = base+i; if (idx < N_NODES) s += count[idx]; }
  sums[t] = s;
  __syncthreads();
  for (int off = 1; off < 1024; off <<= 1){
    int v = (t >= off) ? sums[t-off] : 0;
    __syncthreads();
    sums[t] += v;
    __syncthreads();
  }
  int run = (t > 0) ? sums[t-1] : 0;
  for (int i = 0; i < 20; ++i){
    int idx = base+i;
    if (idx < N_NODES){ cursor[idx] = run; run += count[idx]; }
  }
}

// ---------------- sort pass C: scatter edges into receiver-sorted arrays --------------
__global__ __launch_bounds__(256) void scatter_kernel(
    const int* __restrict__ snd, const int* __restrict__ rcv,
    const float* __restrict__ ev, const float* __restrict__ re,
    int* __restrict__ cursor,
    int* __restrict__ snd_s, int* __restrict__ rcv_s,
    float* __restrict__ ev_s, float* __restrict__ re_s){
  int e = blockIdx.x*256 + threadIdx.x;
  int r = rcv[e];
  int pos = atomicAdd(&cursor[r], 1);
  snd_s[pos] = snd[e];
  rcv_s[pos] = r;
  ev_s[pos*3+0] = ev[e*3+0];
  ev_s[pos*3+1] = ev[e*3+1];
  ev_s[pos*3+2] = ev[e*3+2];
  const float4* rp = (const float4*)&re[(size_t)e*R_DIM];
  float4 ra = rp[0], rb = rp[1];
  float4* op = (float4*)&re_s[(size_t)pos*R_DIM];
  op[0] = ra; op[1] = rb;
}

// ---------------- K2: MFMA radial GEMM + register-resident messages + scatter ---------
__global__ __launch_bounds__(512, 4) void edge_kernel(
    const float* __restrict__ ev_s, const float* __restrict__ re_s,
    const int* __restrict__ snd_s, const int* __restrict__ rcv_s,
    const float* __restrict__ Wr1, const unsigned short* __restrict__ wr2t,
    const float* __restrict__ s_u, const float* __restrict__ v_u,
    float* __restrict__ a_s, float* __restrict__ a_v)
{
  __shared__ __align__(16) float Wr1_l[R_DIM*HR];            // 2 KB
  __shared__ __align__(16) unsigned short Wr2T_l[320*HPAD];  // 43.5 KB bf16 [n][k] padded
  __shared__ __align__(16) unsigned short h_l[TE*HPAD];      // 17.4 KB bf16 [e][k] padded
  __shared__ float u_l[TE][4];
  __shared__ int snd_l[TE];
  __shared__ int rcv_l[TE];

  const int t = threadIdx.x;
  const int lane = t & 63;
  const int w = t >> 6;                 // wave 0..7 = edge row-block
  // bijective XCD swizzle over 2500 blocks (2500 = 8*312 + 4)
  int b = blockIdx.x;
  int xcd = b & 7, idx = b >> 3;
  const int q = NT >> 3, r = NT & 7;
  int tile = (xcd < r ? xcd*(q+1) : r*(q+1) + (xcd-r)*q) + idx;
  const int e0 = tile * TE;

  // ---- stage Wr1 (512 f32), Wr2T (20480 bf16 -> padded), edge meta ----
  Wr1_l[t] = Wr1[t];
  #pragma unroll
  for (int j = 0; j < 10; ++j){
    int i4 = t + 512*j;                 // ushort4 index, 5120 total
    ushort4 v4 = ((const ushort4*)wr2t)[i4];
    int el = i4*4; int n = el >> 6, k = el & 63;
    *(ushort4*)&Wr2T_l[n*HPAD + k] = v4;
  }
  if (t < TE){
    int e = e0 + t;
    float x = ev_s[e*3+0], y = ev_s[e*3+1], z = ev_s[e*3+2];
    float nr = sqrtf(x*x + y*y + z*z);
    float inv = 1.0f / fmaxf(nr, 1e-9f);
    u_l[t][0] = x*inv; u_l[t][1] = y*inv; u_l[t][2] = z*inv;
    snd_l[t] = snd_s[e];
    rcv_l[t] = rcv_s[e];
  }
  __syncthreads();

  // ---- h = silu(re @ Wr1) in bf16: thread (e = t&127, qh = t>>7) does k = qh*16..+16
  {
    int e = t & 127, qh = t >> 7;
    const float4* rp = (const float4*)&re_s[(size_t)(e0 + e)*R_DIM];
    float4 ra = rp[0], rb = rp[1];
    unsigned short hh[16];
    #pragma unroll
    for (int kk = 0; kk < 16; ++kk){
      int k = qh*16 + kk;
      float acc = ra.x*Wr1_l[0*HR+k] + ra.y*Wr1_l[1*HR+k] + ra.z*Wr1_l[2*HR+k] + ra.w*Wr1_l[3*HR+k]
                + rb.x*Wr1_l[4*HR+k] + rb.y*Wr1_l[5*HR+k] + rb.z*Wr1_l[6*HR+k] + rb.w*Wr1_l[7*HR+k];
      hh[kk] = f2bf(acc / (1.0f + expf(-acc)));
    }
    #pragma unroll
    for (int j4 = 0; j4 < 4; ++j4)
      *(ushort4*)&h_l[e*HPAD + qh*16 + j4*4] = *(ushort4*)&hh[j4*4];
  }
  __syncthreads();

  // ---- MFMA: W5[128][320] = h @ Wr2T^T, wave w owns rows w*16..+16, all 20 col-frags
  // v_mfma_f32_16x16x16_bf16 layout: A row=lane&15,k=4*(lane>>4)+j; B col=lane&15,same k;
  // D col=lane&15, row=(lane>>4)*4+reg  (m89-verified C/D mapping)
  f32x4 acc[20];
  #pragma unroll
  for (int cf = 0; cf < 20; ++cf) acc[cf] = (f32x4){0.f,0.f,0.f,0.f};
  {
    const int arow = (w*16 + (lane & 15))*HPAD;
    const int koff = 4*(lane >> 4);
    #pragma unroll
    for (int kt = 0; kt < 4; ++kt){
      bf16x4 af = *(const bf16x4*)&h_l[arow + kt*16 + koff];
      #pragma unroll
      for (int cf = 0; cf < 20; ++cf){
        bf16x4 bf = *(const bf16x4*)&Wr2T_l[(cf*16 + (lane & 15))*HPAD + kt*16 + koff];
        acc[cf] = __builtin_amdgcn_mfma_f32_16x16x16bf16_1k(af, bf, acc[cf], 0, 0, 0);
      }
    }
  }

  // ---- messages, fully register-resident: lane has 4 edges x 4 channel-groups x 5 paths
  // col n = cf*16 + (lane&15) -> path p = cf>>2, channel c = (cf&3)*16 + (lane&15)
  {
    const int ebase = w*16 + (lane >> 4)*4;   // first of this lane's 4 edges
    const int cl = lane & 15;
    float ms[4], mv0[4], mv1[4], mv2[4];
    #pragma unroll
    for (int k2 = 0; k2 < 4; ++k2){ ms[k2]=0.f; mv0[k2]=0.f; mv1[k2]=0.f; mv2[k2]=0.f; }
    int cur = rcv_l[ebase];
    #pragma unroll
    for (int i = 0; i < 4; ++i){
      int el = ebase + i;
      int rc = rcv_l[el];
      if (rc != cur){
        #pragma unroll
        for (int k2 = 0; k2 < 4; ++k2){
          int c = k2*16 + cl;
          unsafeAtomicAdd(&a_s[cur*C + c],       ms[k2]);
          unsafeAtomicAdd(&a_v[(cur*3+0)*C + c], mv0[k2]);
          unsafeAtomicAdd(&a_v[(cur*3+1)*C + c], mv1[k2]);
          unsafeAtomicAdd(&a_v[(cur*3+2)*C + c], mv2[k2]);
          ms[k2]=0.f; mv0[k2]=0.f; mv1[k2]=0.f; mv2[k2]=0.f;
        }
        cur = rc;
      }
      int sn = snd_l[el];
      float u0 = u_l[el][0], u1 = u_l[el][1], u2 = u_l[el][2];
      const float* sp_ = &s_u[sn*C];
      const float* vp_ = &v_u[sn*3*C];
      #pragma unroll
      for (int k2 = 0; k2 < 4; ++k2){
        int c = k2*16 + cl;
        float se  = sp_[c];
        float ve0 = vp_[c];
        float ve1 = vp_[C + c];
        float ve2 = vp_[2*C + c];
        float w0 = acc[0*4+k2][i];
        float w1 = acc[1*4+k2][i];
        float w2 = acc[2*4+k2][i];
        float w3 = acc[3*4+k2][i];
        float w4 = acc[4*4+k2][i];
        float dt  = ve0*u0 + ve1*u1 + ve2*u2;
        float cr0 = ve1*u2 - ve2*u1;
        float cr1 = ve2*u0 - ve0*u2;
        float cr2 = ve0*u1 - ve1*u0;
        ms[k2]  += w0*se + w3*dt;
        mv0[k2] += w1*ve0 + w2*u0 + w4*cr0;
        mv1[k2] += w1*ve1 + w2*u1 + w4*cr1;
        mv2[k2] += w1*ve2 + w2*u2 + w4*cr2;
      }
    }
    #pragma unroll
    for (int k2 = 0; k2 < 4; ++k2){
      int c = k2*16 + cl;
      unsafeAtomicAdd(&a_s[cur*C + c],       ms[k2]);
      unsafeAtomicAdd(&a_v[(cur*3+0)*C + c], mv0[k2]);
      unsafeAtomicAdd(&a_v[(cur*3+1)*C + c], mv1[k2]);
      unsafeAtomicAdd(&a_v[(cur*3+2)*C + c], mv2[k2]);
    }
  }
}

// ---------------- K3: down-matvec, product basis, soft-norm, residual, readout (4/blk)
__global__ __launch_bounds__(256) void node_post_kernel(
    const float* __restrict__ a_s, const float* __restrict__ a_v,
    const float* __restrict__ fs_in, const float* __restrict__ fv_in,
    const int* __restrict__ species,
    const float* __restrict__ W_rs, const float* __restrict__ W_rv,
    const float* __restrict__ W_ds, const float* __restrict__ W_dv,
    const float* __restrict__ w1s, const float* __restrict__ w1v,
    const float* __restrict__ w2ss, const float* __restrict__ w2vv, const float* __restrict__ w2sv,
    const float* __restrict__ W_ps, const float* __restrict__ W_pv,
    const float* __restrict__ w_read, float* __restrict__ out)
{
  const int ni = threadIdx.x >> 6;
  const int d  = threadIdx.x & 63;
  const int n  = blockIdx.x*4 + ni;
  const int sp = species[n];
  __shared__ float as_l[4][C];
  __shared__ float av_l[4][3][C];
  __shared__ float si_l[4][C];
  __shared__ float vi_l[4][3][C];
  as_l[ni][d] = a_s[n*C + d];
  #pragma unroll
  for (int x=0;x<3;x++) av_l[ni][x][d] = a_v[(n*3+x)*C + d];
  si_l[ni][d] = fs_in[n*C + d];
  #pragma unroll
  for (int x=0;x<3;x++) vi_l[ni][x][d] = fv_in[(n*C + d)*3 + x];
  __syncthreads();
  const float* Wrs_p = W_rs + sp*C*C;
  const float* Wrv_p = W_rv + sp*C*C;
  float bs=0, bv0=0, bv1=0, bv2=0, rs=0, rv0=0, rv1=0, rv2=0;
  for (int c=0;c<C;++c){
    float wds = W_ds[c*C+d], wdv = W_dv[c*C+d];
    float wrs = Wrs_p[c*C+d], wrv = Wrv_p[c*C+d];
    bs  += as_l[ni][c]*wds;
    bv0 += av_l[ni][0][c]*wdv; bv1 += av_l[ni][1][c]*wdv; bv2 += av_l[ni][2][c]*wdv;
    rs  += si_l[ni][c]*wrs;
    rv0 += vi_l[ni][0][c]*wrv; rv1 += vi_l[ni][1][c]*wrv; rv2 += vi_l[ni][2][c]*wrv;
  }
  float vv = bv0*bv0 + bv1*bv1 + bv2*bv2;
  float ps  = w1s[sp*C+d]*bs + w2ss[sp*C+d]*bs*bs + w2vv[sp*C+d]*vv;
  float c1v = w1v[sp*C+d], c2sv = w2sv[sp*C+d];
  float pv0 = c1v*bv0 + c2sv*bs*bv0;
  float pv1 = c1v*bv1 + c2sv*bs*bv1;
  float pv2 = c1v*bv2 + c2sv*bs*bv2;
  __syncthreads();
  as_l[ni][d] = ps; av_l[ni][0][d]=pv0; av_l[ni][1][d]=pv1; av_l[ni][2][d]=pv2;
  __syncthreads();
  float qs=0, qv0=0, qv1=0, qv2=0;
  for (int c=0;c<C;++c){
    float wps = W_ps[c*C+d], wpv = W_pv[c*C+d];
    qs  += as_l[ni][c]*wps;
    qv0 += av_l[ni][0][c]*wpv; qv1 += av_l[ni][1][c]*wpv; qv2 += av_l[ni][2][c]*wpv;
  }
  float fsv = qs * phi_f(fabsf(qs)) + rs;
  float nv = sqrtf(qv0*qv0 + qv1*qv1 + qv2*qv2);
  float ph = phi_f(nv);
  float fv0 = qv0*ph + rv0;
  float fv1 = qv1*ph + rv1;
  float fv2 = qv2*ph + rv2;
  out[FS_OFF + n*C + d] = fsv;
  float* fvo = &out[FV_OFF + (size_t)(n*C + d)*3];
  fvo[0]=fv0; fvo[1]=fv1; fvo[2]=fv2;
  #pragma unroll
  for (int h=0; h<HEADS; ++h){
    float r = fsv * w_read[h*C + d];
    #pragma unroll
    for (int off=32; off>0; off>>=1) r += __shfl_down(r, off);
    if (d == 0) out[n*HEADS + h] = r;
  }
}

extern "C" void kernel_launch(void* const* d_in, const int* in_sizes, int n_in,
                              void* d_out, int out_size, void* d_ws, size_t ws_size,
                              hipStream_t stream)
{
  const float* ev   = (const float*)d_in[0];
  const float* nfs  = (const float*)d_in[1];
  const float* nfv  = (const float*)d_in[2];
  const float* re   = (const float*)d_in[3];
  const int*   spec = (const int*)d_in[4];
  const int*   snd  = (const int*)d_in[5];
  const int*   rcv  = (const int*)d_in[6];
  const float* W_rs = (const float*)d_in[7];
  const float* W_rv = (const float*)d_in[8];
  const float* Wus  = (const float*)d_in[9];
  const float* Wuv  = (const float*)d_in[10];
  const float* Wr1  = (const float*)d_in[11];
  const float* Wr2  = (const float*)d_in[12];
  const float* Wds  = (const float*)d_in[13];
  const float* Wdv  = (const float*)d_in[14];
  const float* w1s  = (const float*)d_in[15];
  const float* w1v  = (const float*)d_in[16];
  const float* w2ss = (const float*)d_in[17];
  const float* w2vv = (const float*)d_in[18];
  const float* w2sv = (const float*)d_in[19];
  const float* Wps  = (const float*)d_in[20];
  const float* Wpv  = (const float*)d_in[21];
  const float* wrd  = (const float*)d_in[22];

  float* out = (float*)d_out;
  float* ws  = (float*)d_ws;
  // ws layout (f32 units)
  float* s_u   = ws;                       // 1,280,000
  float* v_u   = ws +  1280000;            // 3,840,000
  float* a_s   = ws +  5120000;            // 1,280,000
  float* a_v   = ws +  6400000;            // 3,840,000
  int*   count = (int*)(ws + 10240000);    // 20,000
  int*   cursr = (int*)(ws + 10260000);    // 20,000
  int*   snd_s = (int*)(ws + 10280000);    // 320,000
  int*   rcv_s = (int*)(ws + 10600000);    // 320,000
  float* ev_s  = ws + 10920000;            // 960,000
  float* re_s  = ws + 11880000;            // 2,560,000
  unsigned short* wr2t = (unsigned short*)(ws + 14440000);  // 20,480 bf16

  hipMemsetAsync(a_s, 0, (size_t)5120000*sizeof(float), stream);   // a_s + a_v
  hipMemsetAsync(count, 0, (size_t)N_NODES*sizeof(int), stream);

  wr2t_kernel<<<(320*64)/256, 256, 0, stream>>>(Wr2, wr2t);
  node_up_kernel<<<N_NODES/4, 256, 0, stream>>>(nfs, nfv, Wus, Wuv, s_u, v_u);
  hist_kernel<<<E_EDGES/256, 256, 0, stream>>>(rcv, count);
  scan_kernel<<<1, 1024, 0, stream>>>(count, cursr);
  scatter_kernel<<<E_EDGES/256, 256, 0, stream>>>(snd, rcv, ev, re, cursr,
                                                  snd_s, rcv_s, ev_s, re_s);
  edge_kernel<<<NT, 512, 0, stream>>>(ev_s, re_s, snd_s, rcv_s, Wr1, wr2t,
                                      s_u, v_u, a_s, a_v);
  node_post_kernel<<<N_NODES/4, 256, 0, stream>>>(a_s, a_v, nfs, nfv, spec,
      W_rs, W_rv, Wds, Wdv, w1s, w1v, w2ss, w2vv, w2sv, Wps, Wpv, wrd, out);
}